// Round 6
// baseline (307.642 us; speedup 1.0000x reference)
//
#include <hip/hip_runtime.h>

#define N_NODES 100000
#define N_EDGES 1250000
#define FEATS 64
#define NCOPY 8

#define SCAN_CHUNK 1024
#define SCAN_NB ((N_NODES + SCAN_CHUNK - 1) / SCAN_CHUNK)   // 98
#define EDGE_NB ((N_EDGES + 255) / 256)                     // 4883

// ---------------------------------------------------------------------------
// Workspace layout (ints, 16B-aligned blocks):
//   cnt8    [8][100000]  per-copy histogram of dst      (3.2 MB, memset 0)
//   cursor8 [8][100000]  per-copy fill cursors          (3.2 MB, written by pass23)
//   temp    [100000]     per-block exclusive local scan
//   bsum    [128]        per-scan-block totals
//   offs    [100004]     CSR row offsets (padded)
//   csr_src [1250000]    src ids grouped by dst         (5 MB)
// total ~12.3 MB
// ---------------------------------------------------------------------------

// copy index: same formula in count & fill so per-copy sub-counts match exactly
__device__ __forceinline__ int copy_of_block(int b) { return b & (NCOPY - 1); }

__global__ __launch_bounds__(256) void count_kernel(
        const int* __restrict__ dst, int* __restrict__ cnt8) {
    int e = blockIdx.x * 256 + threadIdx.x;
    int c = copy_of_block(blockIdx.x);
    if (e < N_EDGES) atomicAdd(&cnt8[c * N_NODES + dst[e]], 1);
}

// Pass 1: total[n] = sum_c cnt8[c][n]; per-block (1024 nodes) exclusive local
// scan -> temp, block total -> bsum.
__global__ __launch_bounds__(256) void scan_pass1(
        const int* __restrict__ cnt8,
        int* __restrict__ temp,
        int* __restrict__ bsum) {
    __shared__ int lsum[256];
    const int t = threadIdx.x;
    const int base = blockIdx.x * SCAN_CHUNK + t * 4;

    int v0 = 0, v1 = 0, v2 = 0, v3 = 0;
    if (base + 3 < N_NODES) {
#pragma unroll
        for (int c = 0; c < NCOPY; ++c) {
            const int4 v = *(const int4*)(cnt8 + c * N_NODES + base);
            v0 += v.x; v1 += v.y; v2 += v.z; v3 += v.w;
        }
    } else {
#pragma unroll
        for (int c = 0; c < NCOPY; ++c) {
            if (base + 0 < N_NODES) v0 += cnt8[c * N_NODES + base + 0];
            if (base + 1 < N_NODES) v1 += cnt8[c * N_NODES + base + 1];
            if (base + 2 < N_NODES) v2 += cnt8[c * N_NODES + base + 2];
        }
    }
    lsum[t] = v0 + v1 + v2 + v3;
    __syncthreads();
    for (int off = 1; off < 256; off <<= 1) {
        int y = (t >= off) ? lsum[t - off] : 0;
        __syncthreads();
        lsum[t] += y;
        __syncthreads();
    }
    int toff = (t > 0) ? lsum[t - 1] : 0;

    int e0 = toff;
    int e1 = toff + v0;
    int e2 = e1 + v1;
    int e3 = e2 + v2;
    if (base + 3 < N_NODES) {
        *(int4*)(temp + base) = make_int4(e0, e1, e2, e3);
    } else {
        if (base + 0 < N_NODES) temp[base + 0] = e0;
        if (base + 1 < N_NODES) temp[base + 1] = e1;
        if (base + 2 < N_NODES) temp[base + 2] = e2;
    }
    if (t == 255) bsum[blockIdx.x] = lsum[255];
}

// Pass 2+3 merged: every block redundantly scans bsum[98] (cheap), then
// offs[n] = temp[n] + bscan[block];
// cursor8[c][n] = offs[n] + sum_{x<c} cnt8[x][n].
__global__ __launch_bounds__(256) void scan_pass23(
        const int* __restrict__ cnt8,
        const int* __restrict__ temp,
        const int* __restrict__ bsum,
        int* __restrict__ offs,
        int* __restrict__ cursor8) {
    __shared__ int s[128];
    const int t = threadIdx.x;
    if (t < 128) {
        s[t] = (t < SCAN_NB) ? bsum[t] : 0;
    }
    __syncthreads();
    for (int off = 1; off < 128; off <<= 1) {
        int y = 0;
        if (t < 128 && t >= off) y = s[t - off];
        __syncthreads();
        if (t < 128) s[t] += y;
        __syncthreads();
    }
    const int boff = (blockIdx.x > 0) ? s[blockIdx.x - 1] : 0;

    const int base = blockIdx.x * SCAN_CHUNK + t * 4;
#pragma unroll
    for (int j = 0; j < 4; ++j) {
        int i = base + j;
        if (i < N_NODES) {
            int run = temp[i] + boff;
            offs[i] = run;
#pragma unroll
            for (int c = 0; c < NCOPY; ++c) {
                cursor8[c * N_NODES + i] = run;
                run += cnt8[c * N_NODES + i];
            }
        }
    }
    if (blockIdx.x == 0 && t == 0) offs[N_NODES] = N_EDGES;  // dst always in range
}

__global__ __launch_bounds__(256) void fill_kernel(
        const int* __restrict__ src,
        const int* __restrict__ dst,
        int* __restrict__ cursor8,
        int* __restrict__ csr_src) {
    int e = blockIdx.x * 256 + threadIdx.x;
    int c = copy_of_block(blockIdx.x);   // MUST match count_kernel
    if (e < N_EDGES) {
        int pos = atomicAdd(&cursor8[c * N_NODES + dst[e]], 1);
        csr_src[pos] = src[e];
    }
}

// ---------------------------------------------------------------------------
// Fused gather + linear + bias + relu. One wave per node.
// Gather: 16 lanes per h-row (float4/lane) -> 4 edges per wave-instruction.
// Linear: W row in 64 VGPRs per lane (o = lane), row broadcast via b128 LDS.
// ---------------------------------------------------------------------------
__global__ __launch_bounds__(256) void gather_linear_kernel(
        const float* __restrict__ h,
        const int* __restrict__ offs,
        const int* __restrict__ csr_src,
        const float* __restrict__ W,    // [o][k] row-major
        const float* __restrict__ b,
        float* __restrict__ out) {
    __shared__ int   sidx[4][64];
    __shared__ float srow[4][FEATS];

    const int tid  = threadIdx.x;
    const int lane = tid & 63;
    const int wv   = tid >> 6;
    const int sub  = lane >> 4;
    const int fo   = (lane & 15) * 4;

    float wr[FEATS];
#pragma unroll
    for (int kk = 0; kk < 16; ++kk) {
        float4 w4 = *(const float4*)(W + (size_t)lane * FEATS + kk * 4);
        wr[kk * 4 + 0] = w4.x;
        wr[kk * 4 + 1] = w4.y;
        wr[kk * 4 + 2] = w4.z;
        wr[kk * 4 + 3] = w4.w;
    }
    const float bias = b[lane];

    const int n_waves_total = gridDim.x * 4;
    for (int n = blockIdx.x * 4 + wv; n < N_NODES; n += n_waves_total) {
        const int beg = offs[n];
        const int end = offs[n + 1];

        float4 acc = make_float4(0.f, 0.f, 0.f, 0.f);
        for (int base = beg; base < end; base += 64) {
            int m = end - base;
            if (m > 64) m = 64;
            if (lane < m) sidx[wv][lane] = csr_src[base + lane];
            for (int t = 0; t < m; t += 4) {
                int e = t + sub;
                if (e < m) {
                    int s = sidx[wv][e];
                    float4 v = *(const float4*)(h + (size_t)s * FEATS + fo);
                    acc.x += v.x; acc.y += v.y; acc.z += v.z; acc.w += v.w;
                }
            }
        }

        acc.x += __shfl_xor(acc.x, 16, 64);
        acc.y += __shfl_xor(acc.y, 16, 64);
        acc.z += __shfl_xor(acc.z, 16, 64);
        acc.w += __shfl_xor(acc.w, 16, 64);
        acc.x += __shfl_xor(acc.x, 32, 64);
        acc.y += __shfl_xor(acc.y, 32, 64);
        acc.z += __shfl_xor(acc.z, 32, 64);
        acc.w += __shfl_xor(acc.w, 32, 64);

        if (lane < 16) *(float4*)&srow[wv][fo] = acc;

        float o_acc = bias;
#pragma unroll
        for (int k4 = 0; k4 < 16; ++k4) {
            float4 r = *(const float4*)&srow[wv][k4 * 4];
            o_acc = fmaf(r.x, wr[k4 * 4 + 0], o_acc);
            o_acc = fmaf(r.y, wr[k4 * 4 + 1], o_acc);
            o_acc = fmaf(r.z, wr[k4 * 4 + 2], o_acc);
            o_acc = fmaf(r.w, wr[k4 * 4 + 3], o_acc);
        }
        out[(size_t)n * FEATS + lane] = fmaxf(o_acc, 0.0f);
    }
}

extern "C" void kernel_launch(void* const* d_in, const int* in_sizes, int n_in,
                              void* d_out, int out_size, void* d_ws, size_t ws_size,
                              hipStream_t stream) {
    const float* h   = (const float*)d_in[0];
    const int*   src = (const int*)d_in[1];
    const int*   dst = (const int*)d_in[2];
    const float* W   = (const float*)d_in[3];
    const float* b   = (const float*)d_in[4];
    float* out = (float*)d_out;

    int* ws      = (int*)d_ws;
    int* cnt8    = ws;                          // 8 * 100000
    int* cursor8 = cnt8 + NCOPY * N_NODES;      // 8 * 100000
    int* temp    = cursor8 + NCOPY * N_NODES;   // 100000
    int* bsum    = temp + N_NODES;              // 128
    int* offs    = bsum + 128;                  // 100004 (padded)
    int* csr_src = offs + 100004;               // 1250000

    hipMemsetAsync(cnt8, 0, NCOPY * N_NODES * sizeof(int), stream);

    count_kernel<<<EDGE_NB, 256, 0, stream>>>(dst, cnt8);
    scan_pass1<<<SCAN_NB, 256, 0, stream>>>(cnt8, temp, bsum);
    scan_pass23<<<SCAN_NB, 256, 0, stream>>>(cnt8, temp, bsum, offs, cursor8);
    fill_kernel<<<EDGE_NB, 256, 0, stream>>>(src, dst, cursor8, csr_src);
    gather_linear_kernel<<<2048, 256, 0, stream>>>(h, offs, csr_src, W, b, out);
}

// Round 7
// 200.407 us; speedup vs baseline: 1.5351x; 1.5351x over previous
//
#include <hip/hip_runtime.h>

#define N_NODES 100000
#define N_EDGES 1250000
#define FEATS 64

#define NPB   256                              // nodes per bucket (= blockDim of binB)
#define NBUCK ((N_NODES + NPB - 1) / NPB)      // 391
#define CAP   4096                             // slots/bucket; avg 3197, +16 sigma
#define TILE  2048
#define NTILES ((N_EDGES + TILE - 1) / TILE)   // 611

// ---------------------------------------------------------------------------
// ws layout (ints):
//   cursor [512]          bucket write cursors (init: b*CAP)
//   ebase  [512]          bucket edge-base (exclusive scan of sizes)
//   offs   [100004]       CSR row offsets
//   csr_src[1250000]      src ids grouped by dst
//   pairs  int2[391*4096] bucketed (dst,src) pairs (12.8 MB)
// total ~18.2 MB
// ---------------------------------------------------------------------------

__global__ __launch_bounds__(512) void init_kernel(int* __restrict__ cursor) {
    int t = threadIdx.x;
    if (t < NBUCK) cursor[t] = t * CAP;
}

// Pass A: bin edges into 391 coarse buckets by dst>>8.
// Per tile: LDS histogram gives per-edge local rank; one global atomicAdd per
// (tile,bucket) reserves a contiguous run -> writes are short dense runs.
__global__ __launch_bounds__(256) void binA_kernel(
        const int* __restrict__ src,
        const int* __restrict__ dst,
        int* __restrict__ cursor,
        int2* __restrict__ pairs) {
    __shared__ int hist[NBUCK];
    __shared__ int base[NBUCK];
    const int t  = threadIdx.x;
    const int e0 = blockIdx.x * TILE + t * 8;
    const bool full = (blockIdx.x + 1) * TILE <= N_EDGES;

    for (int i = t; i < NBUCK; i += 256) hist[i] = 0;
    __syncthreads();

    int d[8], lr[8];
    if (full) {
        int4 a = *(const int4*)(dst + e0);
        int4 q = *(const int4*)(dst + e0 + 4);
        d[0]=a.x; d[1]=a.y; d[2]=a.z; d[3]=a.w;
        d[4]=q.x; d[5]=q.y; d[6]=q.z; d[7]=q.w;
#pragma unroll
        for (int j = 0; j < 8; ++j) lr[j] = atomicAdd(&hist[d[j] >> 8], 1);
    } else {
#pragma unroll
        for (int j = 0; j < 8; ++j) {
            if (e0 + j < N_EDGES) {
                d[j]  = dst[e0 + j];
                lr[j] = atomicAdd(&hist[d[j] >> 8], 1);
            }
        }
    }
    __syncthreads();

    for (int i = t; i < NBUCK; i += 256)
        base[i] = hist[i] ? atomicAdd(&cursor[i], hist[i]) : 0;
    __syncthreads();

    if (full) {
        int4 a = *(const int4*)(src + e0);
        int4 q = *(const int4*)(src + e0 + 4);
        int s[8] = {a.x, a.y, a.z, a.w, q.x, q.y, q.z, q.w};
#pragma unroll
        for (int j = 0; j < 8; ++j) {
            int bk  = d[j] >> 8;
            int pos = base[bk] + lr[j];
            if (pos < (bk + 1) * CAP)           // overflow guard (never hits)
                pairs[pos] = make_int2(d[j], s[j]);
        }
    } else {
#pragma unroll
        for (int j = 0; j < 8; ++j) {
            if (e0 + j < N_EDGES) {
                int bk  = d[j] >> 8;
                int pos = base[bk] + lr[j];
                if (pos < (bk + 1) * CAP)
                    pairs[pos] = make_int2(d[j], src[e0 + j]);
            }
        }
    }
}

// Tiny scan: ebase[b] = exclusive prefix of bucket sizes; ebase[NBUCK] = total.
__global__ __launch_bounds__(512) void bscan_kernel(
        const int* __restrict__ cursor, int* __restrict__ ebase) {
    __shared__ int s[512];
    const int t = threadIdx.x;
    s[t] = (t < NBUCK) ? (cursor[t] - t * CAP) : 0;
    __syncthreads();
    for (int off = 1; off < 512; off <<= 1) {
        int y = (t >= off) ? s[t - off] : 0;
        __syncthreads();
        s[t] += y;
        __syncthreads();
    }
    if (t < NBUCK) ebase[t] = (t > 0) ? s[t - 1] : 0;
    if (t == NBUCK) ebase[NBUCK] = s[NBUCK - 1];
}

// Pass B: one block per bucket. LDS count + scan over 256 local nodes ->
// coalesced offs slice; then scatter src into the bucket's contiguous,
// single-block-owned csr region (lines written once, dense).
__global__ __launch_bounds__(256) void binB_kernel(
        const int2* __restrict__ pairs,
        const int* __restrict__ ebase,
        int* __restrict__ offs,
        int* __restrict__ csr_src) {
    __shared__ int lcnt[NPB];
    __shared__ int lsum[NPB];
    __shared__ int lcur[NPB];
    const int t = threadIdx.x;
    const int b = blockIdx.x;
    const int eb   = ebase[b];
    const int size = ebase[b + 1] - eb;
    const int2* bp = pairs + (size_t)b * CAP;

    lcnt[t] = 0;
    __syncthreads();
    for (int i = t; i < size; i += 256) atomicAdd(&lcnt[bp[i].x & (NPB - 1)], 1);
    __syncthreads();

    lsum[t] = lcnt[t];
    __syncthreads();
    for (int off = 1; off < NPB; off <<= 1) {
        int y = (t >= off) ? lsum[t - off] : 0;
        __syncthreads();
        lsum[t] += y;
        __syncthreads();
    }
    const int excl = (t > 0) ? lsum[t - 1] : 0;
    lcur[t] = excl;
    const int node = b * NPB + t;
    if (node < N_NODES) offs[node] = eb + excl;
    if (b == 0 && t == 0) offs[N_NODES] = ebase[NBUCK];
    __syncthreads();

    for (int i = t; i < size; i += 256) {
        int2 p = bp[i];
        int r = atomicAdd(&lcur[p.x & (NPB - 1)], 1);
        csr_src[eb + r] = p.y;
    }
}

// ---------------------------------------------------------------------------
// Fused gather + linear + bias + relu. One wave per node. (unchanged)
// ---------------------------------------------------------------------------
__global__ __launch_bounds__(256) void gather_linear_kernel(
        const float* __restrict__ h,
        const int* __restrict__ offs,
        const int* __restrict__ csr_src,
        const float* __restrict__ W,    // [o][k] row-major
        const float* __restrict__ b,
        float* __restrict__ out) {
    __shared__ int   sidx[4][64];
    __shared__ float srow[4][FEATS];

    const int tid  = threadIdx.x;
    const int lane = tid & 63;
    const int wv   = tid >> 6;
    const int sub  = lane >> 4;
    const int fo   = (lane & 15) * 4;

    float wr[FEATS];
#pragma unroll
    for (int kk = 0; kk < 16; ++kk) {
        float4 w4 = *(const float4*)(W + (size_t)lane * FEATS + kk * 4);
        wr[kk * 4 + 0] = w4.x;
        wr[kk * 4 + 1] = w4.y;
        wr[kk * 4 + 2] = w4.z;
        wr[kk * 4 + 3] = w4.w;
    }
    const float bias = b[lane];

    const int n_waves_total = gridDim.x * 4;
    for (int n = blockIdx.x * 4 + wv; n < N_NODES; n += n_waves_total) {
        const int beg = offs[n];
        const int end = offs[n + 1];

        float4 acc = make_float4(0.f, 0.f, 0.f, 0.f);
        for (int base = beg; base < end; base += 64) {
            int m = end - base;
            if (m > 64) m = 64;
            if (lane < m) sidx[wv][lane] = csr_src[base + lane];
            for (int t = 0; t < m; t += 4) {
                int e = t + sub;
                if (e < m) {
                    int s = sidx[wv][e];
                    float4 v = *(const float4*)(h + (size_t)s * FEATS + fo);
                    acc.x += v.x; acc.y += v.y; acc.z += v.z; acc.w += v.w;
                }
            }
        }

        acc.x += __shfl_xor(acc.x, 16, 64);
        acc.y += __shfl_xor(acc.y, 16, 64);
        acc.z += __shfl_xor(acc.z, 16, 64);
        acc.w += __shfl_xor(acc.w, 16, 64);
        acc.x += __shfl_xor(acc.x, 32, 64);
        acc.y += __shfl_xor(acc.y, 32, 64);
        acc.z += __shfl_xor(acc.z, 32, 64);
        acc.w += __shfl_xor(acc.w, 32, 64);

        if (lane < 16) *(float4*)&srow[wv][fo] = acc;

        float o_acc = bias;
#pragma unroll
        for (int k4 = 0; k4 < 16; ++k4) {
            float4 r = *(const float4*)&srow[wv][k4 * 4];
            o_acc = fmaf(r.x, wr[k4 * 4 + 0], o_acc);
            o_acc = fmaf(r.y, wr[k4 * 4 + 1], o_acc);
            o_acc = fmaf(r.z, wr[k4 * 4 + 2], o_acc);
            o_acc = fmaf(r.w, wr[k4 * 4 + 3], o_acc);
        }
        out[(size_t)n * FEATS + lane] = fmaxf(o_acc, 0.0f);
    }
}

extern "C" void kernel_launch(void* const* d_in, const int* in_sizes, int n_in,
                              void* d_out, int out_size, void* d_ws, size_t ws_size,
                              hipStream_t stream) {
    const float* h   = (const float*)d_in[0];
    const int*   src = (const int*)d_in[1];
    const int*   dst = (const int*)d_in[2];
    const float* W   = (const float*)d_in[3];
    const float* b   = (const float*)d_in[4];
    float* out = (float*)d_out;

    int* ws      = (int*)d_ws;
    int* cursor  = ws;                       // 512
    int* ebase   = cursor + 512;             // 512
    int* offs    = ebase + 512;              // 100004
    int* csr_src = offs + 100004;            // 1250000
    int2* pairs  = (int2*)(csr_src + N_EDGES);  // 391*4096 int2 (8B-aligned: prefix is even)

    init_kernel<<<1, 512, 0, stream>>>(cursor);
    binA_kernel<<<NTILES, 256, 0, stream>>>(src, dst, cursor, pairs);
    bscan_kernel<<<1, 512, 0, stream>>>(cursor, ebase);
    binB_kernel<<<NBUCK, 256, 0, stream>>>(pairs, ebase, offs, csr_src);
    gather_linear_kernel<<<2048, 256, 0, stream>>>(h, offs, csr_src, W, b, out);
}